// Round 7
// baseline (138.395 us; speedup 1.0000x reference)
//
#include <hip/hip_runtime.h>

// GraphConvolution: out = relu(D^-1/2 (2I - adj) D^-1/2 (input@weight) + b)
// N=8192, F_in=512, F_out=256. fp16 MFMA internally (needs 2^-12 rounding).
//
// R7: k3 BK 64->256. Per-row adj reads become 1KB contiguous (HBM-friendly),
// barriers drop 4x (one per 256-k step), and every pipeline wait gains 4x
// latency slack (sub-phase ~3200cy >> 900cy HBM latency). 4 sub-phases per
// step: {issue B(sp+1) ping-pong + adj quarter, counted vmcnt, 16 MFMA}.
// 4 vm ops stay in flight across every barrier (T4).

typedef _Float16 h4 __attribute__((ext_vector_type(4)));
typedef _Float16 h8 __attribute__((ext_vector_type(8)));
typedef float f4 __attribute__((ext_vector_type(4)));

__device__ __forceinline__ void gload_lds16(const void* g, void* l) {
    __builtin_amdgcn_global_load_lds(
        (const __attribute__((address_space(1))) void*)g,
        (__attribute__((address_space(3))) void*)l, 16, 0, 0);
}

// two 16B loads via inline asm: compiler cannot attach its own vmcnt(0)
__device__ __forceinline__ void gload2(const float* p, f4& x, f4& y) {
    asm volatile("global_load_dwordx4 %0, %2, off\n\t"
                 "global_load_dwordx4 %1, %2, off offset:16"
                 : "=&v"(x), "=&v"(y)
                 : "v"(p)
                 : "memory");
}
// B fragment pair from fragT chunk: kk=0 at +0, kk=1 at +1024 (coalesced 1KB)
__device__ __forceinline__ void gloadBfrag(const char* p, h8& x, h8& y) {
    asm volatile("global_load_dwordx4 %0, %2, off\n\t"
                 "global_load_dwordx4 %1, %2, off offset:1024"
                 : "=&v"(x), "=&v"(y)
                 : "v"(p)
                 : "memory");
}

// ---------------------------------------------------------------------------
// k0: weight [512][256] f32 -> W^T [256 j][512 k] fp16, XOR-swizzled within
// each 128B k-chunk: byte ^= ((j&7)<<4)  (consumed by k2's gload_lds path).
__global__ __launch_bounds__(256) void k0_wt(const float* __restrict__ weight,
                                             char* __restrict__ wt) {
    const int idx = blockIdx.x * 256 + threadIdx.x;   // 131072 total
    const int k = idx >> 8, j = idx & 255;
    const _Float16 h = (_Float16)weight[idx];
    const int off = j * 1024 + ((k >> 6) << 7) + (((k & 63) << 1) ^ ((j & 7) << 4));
    *(_Float16*)(wt + off) = h;
}

// ---------------------------------------------------------------------------
// k1: dinv[r] = 1/sqrt(2 + sum_k adj[r][k])
__global__ __launch_bounds__(256) void k1_deg(const float* __restrict__ adj,
                                              float* __restrict__ dinv) {
    const int r = blockIdx.x;
    const float4* rp = (const float4*)(adj + (size_t)r * 8192);
    const int t = threadIdx.x;
    float s = 0.f;
#pragma unroll
    for (int i = 0; i < 8; ++i) {
        float4 v = rp[t + i * 256];
        s += (v.x + v.y) + (v.z + v.w);
    }
#pragma unroll
    for (int off = 32; off > 0; off >>= 1) s += __shfl_down(s, off, 64);
    __shared__ float part[4];
    if ((t & 63) == 0) part[t >> 6] = s;
    __syncthreads();
    if (t == 0) {
        float deg = (part[0] + part[1]) + (part[2] + part[3]);
        dinv[r] = 1.0f / sqrtf(2.0f + deg);
    }
}

// ---------------------------------------------------------------------------
// fragT layout of S'^T (4 MB): for j in [0,256), k in [0,8192):
//   chunk = (j>>4)*128 + (k>>6)            (2048 B each)
//   off   = chunk*2048 + ((k>>5)&1)*1024 + (((k>>3)&3)*16 + (j&15))*16 + (k&7)*2
// Lane l of a wave reading chunk base + l*16 gets exactly its MFMA B-fragment.
// ---------------------------------------------------------------------------
// k2: support = input @ weight; writes S' = dinv[k]*support[k][j] into fragT.
__global__ __launch_bounds__(512) void k2_support(const float* __restrict__ input,
                                                  const char* __restrict__ wt,
                                                  const float* __restrict__ dinv,
                                                  char* __restrict__ sT) {
    __shared__ char smem[4096 + 32768];   // A [32][128B] + B [256][128B]
    const int t = threadIdx.x, w = t >> 6, l = t & 63;
    const int r0 = (int)blockIdx.x * 32;
    const int arow = t >> 4, ak4 = t & 15;
    const int bj = l >> 3, bb = (l & 7) * 16;

    f4 acc[2][2] = {};

    for (int kt = 0; kt < 8; ++kt) {
        const int k0 = kt * 64;
        __syncthreads();
        // stage A: 32 rows x 64 k fp16, swizzled
        {
            float4 v = *(const float4*)(input + (size_t)(r0 + arow) * 512 + k0 + ak4 * 4);
            h4 h;
            h[0] = (_Float16)v.x; h[1] = (_Float16)v.y;
            h[2] = (_Float16)v.z; h[3] = (_Float16)v.w;
            *(h4*)(smem + arow * 128 + ((ak4 * 8) ^ ((arow & 7) << 4))) = h;
        }
        // stage B: W^T tile [256][64] fp16 via global_load_lds (pre-swizzled)
#pragma unroll
        for (int q = 0; q < 4; ++q) {
            const int c = q * 8 + w;
            gload_lds16(wt + (size_t)(c * 8 + bj) * 1024 + kt * 128 + bb,
                        smem + 4096 + c * 1024);
        }
        __syncthreads();
#pragma unroll
        for (int kk = 0; kk < 2; ++kk) {
            const int ko = kk * 64 + ((l >> 4) << 4);
            h8 a[2], b[2];
#pragma unroll
            for (int m = 0; m < 2; ++m) {
                const int r = m * 16 + (l & 15);
                a[m] = *(const h8*)(smem + r * 128 + (ko ^ ((r & 7) << 4)));
            }
#pragma unroll
            for (int n = 0; n < 2; ++n) {
                const int j = w * 32 + n * 16 + (l & 15);
                b[n] = *(const h8*)(smem + 4096 + j * 128 + (ko ^ ((j & 7) << 4)));
            }
#pragma unroll
            for (int m = 0; m < 2; ++m)
#pragma unroll
                for (int n = 0; n < 2; ++n)
                    acc[m][n] = __builtin_amdgcn_mfma_f32_16x16x32_f16(a[m], b[n], acc[m][n], 0, 0, 0);
        }
    }
    // epilogue -> fragT. C/D: col=l&15, row=(l>>4)*4+reg.
#pragma unroll
    for (int m = 0; m < 2; ++m)
#pragma unroll
        for (int n = 0; n < 2; ++n) {
            const int j = w * 32 + n * 16 + (l & 15);
            const int k0r = r0 + m * 16 + ((l >> 4) << 2);
            h4 h;
#pragma unroll
            for (int r = 0; r < 4; ++r)
                h[r] = (_Float16)(dinv[k0r + r] * acc[m][n][r]);
            const int off = (((j >> 4) * 128 + (k0r >> 6)) << 11) +
                            (((k0r >> 5) & 1) << 10) +
                            ((((k0r >> 3) & 3) << 4) + (j & 15)) * 16 +
                            ((k0r & 7) << 1);
            *(h4*)(sT + off) = h;
        }
}

// ---------------------------------------------------------------------------
// k3: partial[i][j] = sum_{k in split} (2I - adj)[i][k] * S'T[j][k]
// BM=64, BN=256, BK=256; 8 waves, wave tile 64Mx32N. Grid (128, nsplit),
// 2 blocks/CU. A double-buffered in LDS (2x32KB, 512B rows, XOR-swizzled);
// B ping-pong regs from fragT (coalesced). 4 sub-phases/step, 1 barrier/step.
__global__ __launch_bounds__(512, 4) void k3_spmm(const float* __restrict__ adj,
                                                  const char* __restrict__ sT,
                                                  float* __restrict__ part,
                                                  float* __restrict__ out,
                                                  int steps) {
    __shared__ __align__(16) char smem[2][32768];  // A: [64 rows][512 B] each
    const int t = threadIdx.x;
    const int w = t >> 6, l = t & 63;
    const int i0 = (int)blockIdx.x * 64;
    const int ks0 = (int)blockIdx.y * steps * 256;
    const int ts_d = ((unsigned)(i0 - ks0) < (unsigned)(steps * 256))
                     ? ((i0 - ks0) >> 8) : -1;   // uniform diag step (or -1)

    // A staging: row = t>>3 (0..63); 8 threads/row; per round r (0,1) thread
    // covers 16 consecutive f32 at k-offset (t&7)*16 + r*128 within the step.
    const int arow = t >> 3;
    const int ak16 = (t & 7) * 16;
    const int arow_g = i0 + arow;
    const float* aptr = adj + (size_t)arow_g * 8192 + ks0 + ak16;
    const int aswz = (arow & 7) << 4;
    const int abase = arow * 512;

    // fragT pointers for this wave's two j-blocks
    const char* bpn0 = sT + ((size_t)(w * 2) * 128 + (ks0 >> 6)) * 2048 + l * 16;
    const char* bpn1 = bpn0 + 262144;   // +128 chunks

    f4 acc[4][2] = {};
    h8 bvA[2][2], bvB[2][2];            // [kk][n] ping-pong B fragments
    f4 pa0, pa1, pa2, pa3;              // adj round regs (16 f32)
    f4 pb0, pb1, pb2, pb3;

    auto loadB = [&](int s, h8 (&bv)[2][2]) {      // s = global sub-phase idx
        gloadBfrag(bpn0 + (size_t)s * 2048, bv[0][0], bv[1][0]);
        gloadBfrag(bpn1 + (size_t)s * 2048, bv[0][1], bv[1][1]);
    };
    auto loadAr = [&](int tile, int r, f4& x0, f4& y0, f4& x1, f4& y1) {
        const float* p = aptr + (size_t)tile * 256 + r * 128;
        gload2(p, x0, y0);
        gload2(p + 8, x1, y1);
    };
    auto writeAr = [&](char* buf, int tile, int r,
                       const f4 x0, const f4 y0, const f4 x1, const f4 y1) {
        h8 u, v;
        if (tile == ts_d) {   // uniform branch
            const int kg = ks0 + tile * 256 + ak16 + r * 128;
#pragma unroll
            for (int e = 0; e < 4; ++e) {
                u[e]     = (_Float16)((arow_g == kg + e     ) ? 2.0f - x0[e] : -x0[e]);
                u[4 + e] = (_Float16)((arow_g == kg + 4 + e ) ? 2.0f - y0[e] : -y0[e]);
                v[e]     = (_Float16)((arow_g == kg + 8 + e ) ? 2.0f - x1[e] : -x1[e]);
                v[4 + e] = (_Float16)((arow_g == kg + 12 + e) ? 2.0f - y1[e] : -y1[e]);
            }
        } else {
#pragma unroll
            for (int e = 0; e < 4; ++e) {
                u[e] = (_Float16)(-x0[e]); u[4 + e] = (_Float16)(-y0[e]);
                v[e] = (_Float16)(-x1[e]); v[4 + e] = (_Float16)(-y1[e]);
            }
        }
        const int kb = (ak16 << 1) + r * 256;     // fp16 byte offset in row
        *(h8*)(buf + abase + (kb ^ aswz)) = u;
        *(h8*)(buf + abase + ((kb + 16) ^ aswz)) = v;
    };
    auto compute = [&](const char* A, int sp, const h8 (&bv)[2][2]) {
#pragma unroll
        for (int kk = 0; kk < 2; ++kk) {
            const int kb = sp * 128 + kk * 64 + ((l >> 4) << 4);
            h8 a[4];
#pragma unroll
            for (int m = 0; m < 4; ++m) {
                const int r = m * 16 + (l & 15);
                a[m] = *(const h8*)(A + r * 512 + (kb ^ ((r & 7) << 4)));
            }
#pragma unroll
            for (int m = 0; m < 4; ++m)
#pragma unroll
                for (int n = 0; n < 2; ++n)
                    acc[m][n] = __builtin_amdgcn_mfma_f32_16x16x32_f16(a[m], bv[kk][n], acc[m][n], 0, 0, 0);
        }
    };

#define SBAR0() __builtin_amdgcn_sched_barrier(0)
#define WAIT_BV(N, BV)                                                        \
    asm volatile("s_waitcnt vmcnt(" #N ")"                                    \
                 : "+v"(BV[0][0]), "+v"(BV[0][1]),                            \
                   "+v"(BV[1][0]), "+v"(BV[1][1]) :: "memory");               \
    SBAR0();
#define WAIT_BVA(N, BV, X0, Y0, X1, Y1)                                       \
    asm volatile("s_waitcnt vmcnt(" #N ")"                                    \
                 : "+v"(BV[0][0]), "+v"(BV[0][1]),                            \
                   "+v"(BV[1][0]), "+v"(BV[1][1]),                            \
                   "+v"(X0), "+v"(Y0), "+v"(X1), "+v"(Y1) :: "memory");       \
    SBAR0();
#define BARRIER()                                                             \
    asm volatile("s_waitcnt lgkmcnt(0)\n\ts_barrier" ::: "memory");           \
    SBAR0();

    // prologue: adj tile0 (rounds 0,1) + B[0]; write A(0); barrier.
    loadAr(0, 0, pa0, pa1, pa2, pa3);           // 4 ops
    loadAr(0, 1, pb0, pb1, pb2, pb3);           // 4 -> 8
    loadB(0, bvA);                              // 4 -> 12
    asm volatile("s_waitcnt vmcnt(8)"
                 : "+v"(pa0), "+v"(pa1), "+v"(pa2), "+v"(pa3) :: "memory");
    SBAR0();
    writeAr(smem[0], 0, 0, pa0, pa1, pa2, pa3);
    asm volatile("s_waitcnt vmcnt(4)"
                 : "+v"(pb0), "+v"(pb1), "+v"(pb2), "+v"(pb3) :: "memory");
    SBAR0();
    writeAr(smem[0], 0, 1, pb0, pb1, pb2, pb3);
    BARRIER()                                    // B[0] (4 ops) stays in flight

    // steady step ts (reads AC, stages tile ts+1 into AN):
    // sp0: +B(4)                 -> 8  : vmcnt(4) consume bvA
    // sp1: +B(4)+adjR0(4)        -> 12 : vmcnt(8) consume bvB
    // sp2: +B(4)                 -> 12 : vmcnt(4) consume bvA+adjR0; writeA R0; +adjR1
    // sp3: +B(4)                 -> 12 : vmcnt(4) consume bvB+adjR1; writeA R1; barrier
    for (int ts = 0; ts + 1 < steps; ++ts) {
        char* AC = smem[ts & 1];
        char* AN = smem[(ts & 1) ^ 1];
        const int s0 = ts * 4;
        loadB(s0 + 1, bvB);
        WAIT_BV(4, bvA)
        compute(AC, 0, bvA);

        loadB(s0 + 2, bvA);
        loadAr(ts + 1, 0, pa0, pa1, pa2, pa3);
        WAIT_BV(8, bvB)
        compute(AC, 1, bvB);

        loadB(s0 + 3, bvB);
        WAIT_BVA(4, bvA, pa0, pa1, pa2, pa3)
        writeAr(AN, ts + 1, 0, pa0, pa1, pa2, pa3);
        loadAr(ts + 1, 1, pb0, pb1, pb2, pb3);
        compute(AC, 2, bvA);

        loadB(s0 + 4, bvA);
        WAIT_BVA(4, bvB, pb0, pb1, pb2, pb3)
        writeAr(AN, ts + 1, 1, pb0, pb1, pb2, pb3);
        compute(AC, 3, bvB);
        BARRIER()
    }
    // final step (no prefetch)
    {
        const char* AC = smem[(steps - 1) & 1];
        const int s0 = (steps - 1) * 4;
        loadB(s0 + 1, bvB);
        WAIT_BV(4, bvA)
        compute(AC, 0, bvA);
        loadB(s0 + 2, bvA);
        WAIT_BV(4, bvB)
        compute(AC, 1, bvB);
        loadB(s0 + 3, bvB);
        WAIT_BV(4, bvA)
        compute(AC, 2, bvA);
        WAIT_BV(0, bvB)
        compute(AC, 3, bvB);
    }
#undef SBAR0
#undef WAIT_BV
#undef WAIT_BVA
#undef BARRIER

    // write f32 partial (last split writes into d_out)
    float* dst = (blockIdx.y == gridDim.y - 1) ? out
               : part + (size_t)blockIdx.y * (8192 * 256);
#pragma unroll
    for (int m = 0; m < 4; ++m)
#pragma unroll
        for (int n = 0; n < 2; ++n) {
            const int j = w * 32 + n * 16 + (l & 15);
            const int ib = i0 + m * 16 + ((l >> 4) << 2);
#pragma unroll
            for (int r = 0; r < 4; ++r)
                dst[(size_t)(ib + r) * 256 + j] = acc[m][n][r];
        }
}

// ---------------------------------------------------------------------------
// k4: out = relu(dinv[i] * (sum of partials) + b[j]); last partial is in out.
__global__ __launch_bounds__(256) void k4_fin(const float* __restrict__ part,
                                              float* __restrict__ out,
                                              const float* __restrict__ dinv,
                                              const float* __restrict__ bias,
                                              int nsplit) {
    const int idx = blockIdx.x * 256 + threadIdx.x;   // 524288 float4 groups
    float4 s = ((const float4*)out)[idx];
    for (int sp = 0; sp < nsplit - 1; ++sp)
        s += ((const float4*)(part + (size_t)sp * (8192 * 256)))[idx];
    const float dv = dinv[idx >> 6];
    const float4 b = ((const float4*)bias)[idx & 63];
    float4 r;
    r.x = fmaxf(dv * s.x + b.x, 0.f);
    r.y = fmaxf(dv * s.y + b.y, 0.f);
    r.z = fmaxf(dv * s.z + b.z, 0.f);
    r.w = fmaxf(dv * s.w + b.w, 0.f);
    ((float4*)out)[idx] = r;
}

// ---------------------------------------------------------------------------
extern "C" void kernel_launch(void* const* d_in, const int* in_sizes, int n_in,
                              void* d_out, int out_size, void* d_ws, size_t ws_size,
                              hipStream_t stream) {
    const float* input  = (const float*)d_in[0];   // [8192][512]
    const float* adj    = (const float*)d_in[1];   // [8192][8192]
    const float* weight = (const float*)d_in[2];   // [512][256]
    const float* bias   = (const float*)d_in[3];   // [256]
    float* out = (float*)d_out;                    // [8192][256]

    char* ws = (char*)d_ws;
    float* dinv = (float*)ws;                         // 32 KB
    char*  wt   = ws + 32768;                         // 256 KB
    char*  sT   = ws + 294912;                        // 4 MB (fp16, fragT)
    float* part = (float*)(ws + 294912 + 4194304);    // (nsplit-1) * 8 MB

    const size_t base = 294912 + 4194304;
    int nsplit = 1;
    if (ws_size >= base + 3 * 8388608) nsplit = 4;        // ~28.3 MB
    else if (ws_size >= base + 1 * 8388608) nsplit = 2;   // ~12.7 MB
    const int steps = 8192 / (nsplit * 256);              // 256-k steps/block

    k0_wt<<<512, 256, 0, stream>>>(weight, wt);
    k1_deg<<<8192, 256, 0, stream>>>(adj, dinv);
    k2_support<<<256, 512, 0, stream>>>(input, wt, dinv, sT);
    k3_spmm<<<dim3(128, nsplit), 512, 0, stream>>>(adj, sT, part, out, steps);
    k4_fin<<<2048, 256, 0, stream>>>(part, out, dinv, bias, nsplit);
}